// Round 10
// baseline (550.734 us; speedup 1.0000x reference)
//
#include <hip/hip_runtime.h>

#define N_NODES 50000
#define N_EDGES 800000
#define D 64          // NODE_DIM == MSG_DIM
#define EDIM 4
#define IN_DIM 132    // 2*D + EDIM
#define H3 192        // 3*D
#define XS 65         // XT row stride (floats): 65%32==1 -> stride-XS accesses 2-way/free

typedef unsigned short ushort;
typedef __attribute__((ext_vector_type(8))) unsigned short ushort8_t;

__device__ __forceinline__ float bf2f(ushort u) {
    union { unsigned int i; float f; } x;
    x.i = ((unsigned int)u) << 16;
    return x.f;
}
__device__ __forceinline__ ushort f2bf(float f) {
    union { float f; unsigned int i; } x;
    x.f = f;
    unsigned int r = x.i + 0x7FFFu + ((x.i >> 16) & 1u);  // round-to-nearest-even
    return (ushort)(r >> 16);
}

// ---------------- CSR build ----------------

__global__ void k_count(const int* __restrict__ dst, int* __restrict__ deg) {
    int e = blockIdx.x * blockDim.x + threadIdx.x;
    if (e < N_EDGES) atomicAdd(&deg[dst[e]], 1);
}

__global__ __launch_bounds__(256) void k_scan1(const int* __restrict__ deg,
                                               int* __restrict__ offsets,
                                               int* __restrict__ bsum) {
    __shared__ int sm[256];
    int tid = threadIdx.x;
    int i = blockIdx.x * 256 + tid;
    int x = (i < N_NODES) ? deg[i] : 0;
    sm[tid] = x;
    __syncthreads();
    for (int s = 1; s < 256; s <<= 1) {
        int v = (tid >= s) ? sm[tid - s] : 0;
        __syncthreads();
        sm[tid] += v;
        __syncthreads();
    }
    if (i < N_NODES) offsets[i] = sm[tid] - x;  // block-local exclusive
    if (tid == 255) bsum[blockIdx.x] = sm[255];
}

__global__ __launch_bounds__(256) void k_scan2(const int* __restrict__ bsum,
                                               int* __restrict__ boff, int nblk) {
    __shared__ int sm[256];
    int tid = threadIdx.x;
    int x = (tid < nblk) ? bsum[tid] : 0;
    sm[tid] = x;
    __syncthreads();
    for (int s = 1; s < 256; s <<= 1) {
        int v = (tid >= s) ? sm[tid - s] : 0;
        __syncthreads();
        sm[tid] += v;
        __syncthreads();
    }
    if (tid < nblk) boff[tid] = sm[tid] - x;  // exclusive
}

__global__ __launch_bounds__(256) void k_scan3(int* __restrict__ offsets,
                                               const int* __restrict__ boff) {
    int i = blockIdx.x * 256 + threadIdx.x;
    if (i < N_NODES) offsets[i] += boff[blockIdx.x];
}

__global__ void k_fill(const int* __restrict__ src, const int* __restrict__ dst,
                       const int* __restrict__ offsets, int* __restrict__ cursor,
                       int* __restrict__ csr_src) {
    int e = blockIdx.x * blockDim.x + threadIdx.x;
    if (e < N_EDGES) {
        int d = dst[e];
        int pos = offsets[d] + atomicAdd(&cursor[d], 1);
        csr_src[pos] = src[e];
    }
}

// ---------------- Hsum (round-invariant): Hsum[n] = sum_{e->n} he[e] ----------------
__global__ void k_hsum(const float* __restrict__ he, const int* __restrict__ dst,
                       float* __restrict__ Hsum) {
    int e = blockIdx.x * blockDim.x + threadIdx.x;
    if (e < N_EDGES) {
        int d = dst[e];
        float4 h = *(const float4*)(he + (size_t)e * EDIM);
        atomicAdd(&Hsum[d * 4 + 0], h.x);
        atomicAdd(&Hsum[d * 4 + 1], h.y);
        atomicAdd(&Hsum[d * 4 + 2], h.z);
        atomicAdd(&Hsum[d * 4 + 3], h.w);
    }
}

// ---------------- hv -> bf16 mirror ----------------
__global__ __launch_bounds__(256) void k_prep(const float* __restrict__ hv,
                                              ushort* __restrict__ hvb) {
    int i = blockIdx.x * blockDim.x + threadIdx.x;  // one thread = 8 elements
    if (i >= (N_NODES * D) / 8) return;
    const float4* p = (const float4*)(hv + (size_t)i * 8);
    float4 a = p[0], b = p[1];
    ushort8_t o;
    o[0] = f2bf(a.x); o[1] = f2bf(a.y); o[2] = f2bf(a.z); o[3] = f2bf(a.w);
    o[4] = f2bf(b.x); o[5] = f2bf(b.y); o[6] = f2bf(b.z); o[7] = f2bf(b.w);
    *(ushort8_t*)(hvb + (size_t)i * 8) = o;
}

// ---------------- fused per-round kernel: gather-sum + GEMMs + GRU ----------------
// 512 threads = 8 waves; 64 nodes per block.
// XT[k][n], k-major, stride XS=65.
//   rows 0..63: S^T (gathered) then a^T; 64..127: hv^T (fp32); 128..131: Hsum^T.
// Phase A2 gather: wave w owns nodes w*8..w*8+7 sequentially. Per edge the whole
// wave reads one bf16 node row (64 lanes x ushort = 128B coalesced); lane k owns feature
// k, so no cross-lane reduce and the S^T store is one conflict-free LDS write per lane.
// csr_src index loads are wave-uniform (readfirstlane'd base) -> scalar pipe; 8 edges
// batched so 8 gathers are in flight per wave (R8 evidence: miss-path latency-bound).

template <int ROUND>
__global__ __launch_bounds__(512) void k_fused(const float* __restrict__ hv_in,
                                               const ushort* __restrict__ hvb_in,
                                               ushort* __restrict__ hvb_out,
                                               const int* __restrict__ csr_src,
                                               const int* __restrict__ offsets,
                                               const int* __restrict__ deg,
                                               const float* __restrict__ Hsum,
                                               const float* __restrict__ W_msg,
                                               const float* __restrict__ b_msg,
                                               const float* __restrict__ W_ih,
                                               const float* __restrict__ W_hh,
                                               const float* __restrict__ b_ih,
                                               const float* __restrict__ b_hh,
                                               float* __restrict__ hv_out) {
    __shared__ float XT[IN_DIM * XS];  // 34320 B

    const int tid = threadIdx.x;
    const int n_base = blockIdx.x * D;
    const int lane = tid & 63;

    // ---- phase A1: stage hv^T (rows 64..127, fp32) + Hsum^T (rows 128..131) ----
    {
        int nl = tid >> 3;  // 0..63
        int c8 = tid & 7;   // 8-float chunk
        int n = n_base + nl;
        if (n >= N_NODES) n = N_NODES - 1;
        const float4* Hp = (const float4*)(hv_in + (size_t)n * D);
        float4 h0 = Hp[c8 * 2], h1 = Hp[c8 * 2 + 1];
        int k0 = c8 * 8;
        XT[(64 + k0 + 0) * XS + nl] = h0.x; XT[(64 + k0 + 1) * XS + nl] = h0.y;
        XT[(64 + k0 + 2) * XS + nl] = h0.z; XT[(64 + k0 + 3) * XS + nl] = h0.w;
        XT[(64 + k0 + 4) * XS + nl] = h1.x; XT[(64 + k0 + 5) * XS + nl] = h1.y;
        XT[(64 + k0 + 6) * XS + nl] = h1.z; XT[(64 + k0 + 7) * XS + nl] = h1.w;
        if (c8 == 0) {
            float4 hs = *(const float4*)(Hsum + (size_t)n * EDIM);
            XT[128 * XS + nl] = hs.x; XT[129 * XS + nl] = hs.y;
            XT[130 * XS + nl] = hs.z; XT[131 * XS + nl] = hs.w;
        }
    }

    // ---- phase A2: gather S^T; wave w owns nodes w*8..w*8+7; lane = feature ----
    {
        const int w8 = (tid >> 6) << 3;
        for (int q = 0; q < 8; ++q) {
            const int nl = w8 + q;
            int n = n_base + nl;
            if (n >= N_NODES) n = N_NODES - 1;
            const int off = __builtin_amdgcn_readfirstlane(offsets[n]);
            const int cnt = __builtin_amdgcn_readfirstlane(deg[n]);
            float acc = 0.f;
            int e = 0;
            for (; e + 8 <= cnt; e += 8) {
                // 8 wave-uniform index loads (scalar pipe), then 8 independent gathers
                int s0 = csr_src[off + e + 0];
                int s1 = csr_src[off + e + 1];
                int s2 = csr_src[off + e + 2];
                int s3 = csr_src[off + e + 3];
                int s4 = csr_src[off + e + 4];
                int s5 = csr_src[off + e + 5];
                int s6 = csr_src[off + e + 6];
                int s7 = csr_src[off + e + 7];
                float v0 = bf2f(hvb_in[(size_t)s0 * D + lane]);
                float v1 = bf2f(hvb_in[(size_t)s1 * D + lane]);
                float v2 = bf2f(hvb_in[(size_t)s2 * D + lane]);
                float v3 = bf2f(hvb_in[(size_t)s3 * D + lane]);
                float v4 = bf2f(hvb_in[(size_t)s4 * D + lane]);
                float v5 = bf2f(hvb_in[(size_t)s5 * D + lane]);
                float v6 = bf2f(hvb_in[(size_t)s6 * D + lane]);
                float v7 = bf2f(hvb_in[(size_t)s7 * D + lane]);
                acc += ((v0 + v1) + (v2 + v3)) + ((v4 + v5) + (v6 + v7));
            }
            for (; e < cnt; ++e) {
                int s = csr_src[off + e];
                acc += bf2f(hvb_in[(size_t)s * D + lane]);
            }
            XT[lane * XS + nl] = acc;  // bank=(lane+nl)%32: 2-way, free
        }
    }
    __syncthreads();

    // ---- phase B: GEMM1 (acc1 = S@Wa + Hsum@Wc, acc2 = hv@Wb) ----
    const int w = __builtin_amdgcn_readfirstlane(tid) >> 6;  // wave id 0..7 (uniform)
    const int jb = w * 8;
    const int n = n_base + lane;
    const bool nvalid = (n < N_NODES);
    const int nc = nvalid ? n : N_NODES - 1;
    const float degf = (float)deg[nc];

    const float* __restrict__ Wm = W_msg + (size_t)ROUND * IN_DIM * D;

    float acc1[8], acc2[8];
#pragma unroll
    for (int i = 0; i < 8; ++i) { acc1[i] = 0.f; acc2[i] = 0.f; }

#pragma unroll 4
    for (int k = 0; k < 64; ++k) {
        float aS = XT[k * XS + lane];
        float aH = XT[(64 + k) * XS + lane];
        const float* wr1 = Wm + k * D + jb;
        const float* wr2 = Wm + (64 + k) * D + jb;
#pragma unroll
        for (int i = 0; i < 8; ++i) {
            acc1[i] = fmaf(aS, wr1[i], acc1[i]);
            acc2[i] = fmaf(aH, wr2[i], acc2[i]);
        }
    }
#pragma unroll
    for (int q = 0; q < 4; ++q) {
        float aQ = XT[(128 + q) * XS + lane];
        const float* wr = Wm + (128 + q) * D + jb;
#pragma unroll
        for (int i = 0; i < 8; ++i) acc1[i] = fmaf(aQ, wr[i], acc1[i]);
    }

    const float* bmp = b_msg + (size_t)ROUND * D + jb;
    float av[8];
#pragma unroll
    for (int i = 0; i < 8; ++i) av[i] = acc1[i] + degf * (acc2[i] + bmp[i]);

    __syncthreads();  // all waves done reading S rows
#pragma unroll
    for (int i = 0; i < 8; ++i) XT[(jb + i) * XS + lane] = av[i];  // a^T into rows 0..63
    __syncthreads();

    // ---- phase C: GEMM2 + GRU ----
    const float* __restrict__ Wi = W_ih + (size_t)ROUND * D * H3;
    const float* __restrict__ Wh = W_hh + (size_t)ROUND * D * H3;
    const float* bi = b_ih + (size_t)ROUND * H3;
    const float* bh = b_hh + (size_t)ROUND * H3;

    float aR[8], aZ[8], aN[8], aHN[8];
#pragma unroll
    for (int i = 0; i < 8; ++i) {
        aR[i] = bi[jb + i] + bh[jb + i];
        aZ[i] = bi[64 + jb + i] + bh[64 + jb + i];
        aN[i] = bi[128 + jb + i];
        aHN[i] = bh[128 + jb + i];
    }

#pragma unroll 4
    for (int k = 0; k < 64; ++k) {  // A = a^T rows, B = Wi
        float Aa = XT[k * XS + lane];
        const float* wr = Wi + k * H3;
#pragma unroll
        for (int i = 0; i < 8; ++i) {
            aR[i] = fmaf(Aa, wr[jb + i], aR[i]);
            aZ[i] = fmaf(Aa, wr[64 + jb + i], aZ[i]);
            aN[i] = fmaf(Aa, wr[128 + jb + i], aN[i]);
        }
    }
#pragma unroll 4
    for (int k = 0; k < 64; ++k) {  // A = hv^T rows, B = Wh
        float Ah = XT[(64 + k) * XS + lane];
        const float* wr = Wh + k * H3;
#pragma unroll
        for (int i = 0; i < 8; ++i) {
            aR[i] = fmaf(Ah, wr[jb + i], aR[i]);
            aZ[i] = fmaf(Ah, wr[64 + jb + i], aZ[i]);
            aHN[i] = fmaf(Ah, wr[128 + jb + i], aHN[i]);
        }
    }

    float o[8];
#pragma unroll
    for (int i = 0; i < 8; ++i) {
        float r = 1.f / (1.f + __expf(-aR[i]));
        float z = 1.f / (1.f + __expf(-aZ[i]));
        float nin = aN[i] + r * aHN[i];
        float nn = 2.f / (1.f + __expf(-2.f * nin)) - 1.f;  // tanh
        float hold = XT[(64 + jb + i) * XS + lane];
        o[i] = (1.f - z) * nn + z * hold;
    }
    if (nvalid) {
        float4* op = (float4*)(hv_out + (size_t)n * D + jb);
        op[0] = make_float4(o[0], o[1], o[2], o[3]);
        op[1] = make_float4(o[4], o[5], o[6], o[7]);
        if (ROUND == 0) {  // bf16 mirror for round-1 gather
            ushort8_t ob;
#pragma unroll
            for (int i = 0; i < 8; ++i) ob[i] = f2bf(o[i]);
            *(ushort8_t*)(hvb_out + (size_t)n * D + jb) = ob;
        }
    }
}

// ---------------- launch ----------------

extern "C" void kernel_launch(void* const* d_in, const int* in_sizes, int n_in,
                              void* d_out, int out_size, void* d_ws, size_t ws_size,
                              hipStream_t stream) {
    const float* hv = (const float*)d_in[0];
    const float* he = (const float*)d_in[1];
    const float* W_msg = (const float*)d_in[2];
    const float* b_msg = (const float*)d_in[3];
    const float* W_ih = (const float*)d_in[4];
    const float* W_hh = (const float*)d_in[5];
    const float* b_ih = (const float*)d_in[6];
    const float* b_hh = (const float*)d_in[7];
    const int* src = (const int*)d_in[8];
    const int* dst = (const int*)d_in[9];
    float* out = (float*)d_out;

    char* p = (char*)d_ws;
    int* deg = (int*)p;        p += (size_t)N_NODES * sizeof(int);
    int* cursor = (int*)p;     p += (size_t)N_NODES * sizeof(int);
    int* offsets = (int*)p;    p += (size_t)N_NODES * sizeof(int);
    int* bsum = (int*)p;       p += 256 * sizeof(int);
    int* boff = (int*)p;       p += 256 * sizeof(int);
    int* csr_src = (int*)p;    p += (size_t)N_EDGES * sizeof(int);
    float* Hsum = (float*)p;   p += (size_t)N_NODES * EDIM * sizeof(float);
    float* hv_buf = (float*)p; p += (size_t)N_NODES * D * sizeof(float);
    ushort* hvb_A = (ushort*)p; p += (size_t)N_NODES * D * sizeof(ushort);
    ushort* hvb_B = (ushort*)p; p += (size_t)N_NODES * D * sizeof(ushort);

    const int NBLK = (N_NODES + 255) / 256;  // 196

    hipMemsetAsync(deg, 0, N_NODES * sizeof(int), stream);
    hipMemsetAsync(cursor, 0, N_NODES * sizeof(int), stream);
    hipMemsetAsync(Hsum, 0, (size_t)N_NODES * EDIM * sizeof(float), stream);

    k_count<<<(N_EDGES + 255) / 256, 256, 0, stream>>>(dst, deg);
    k_scan1<<<NBLK, 256, 0, stream>>>(deg, offsets, bsum);
    k_scan2<<<1, 256, 0, stream>>>(bsum, boff, NBLK);
    k_scan3<<<NBLK, 256, 0, stream>>>(offsets, boff);
    k_fill<<<(N_EDGES + 255) / 256, 256, 0, stream>>>(src, dst, offsets, cursor, csr_src);
    k_hsum<<<(N_EDGES + 255) / 256, 256, 0, stream>>>(he, dst, Hsum);
    k_prep<<<(N_NODES * D / 8 + 255) / 256, 256, 0, stream>>>(hv, hvb_A);

    const int GBLK = (N_NODES + 63) / 64;  // 64 nodes per block, 512 threads

    // round 0: gather from hvb_A, write hv_buf (fp32) + hvb_B (bf16 mirror)
    k_fused<0><<<GBLK, 512, 0, stream>>>(hv, hvb_A, hvb_B, csr_src, offsets, deg, Hsum,
                                         W_msg, b_msg, W_ih, W_hh, b_ih, b_hh, hv_buf);

    // round 1: gather from hvb_B, write d_out
    k_fused<1><<<GBLK, 512, 0, stream>>>(hv_buf, hvb_B, (ushort*)nullptr, csr_src, offsets,
                                         deg, Hsum, W_msg, b_msg, W_ih, W_hh, b_ih, b_hh,
                                         out);
}

// Round 13
// 413.682 us; speedup vs baseline: 1.3313x; 1.3313x over previous
//
#include <hip/hip_runtime.h>

#define N_NODES 50000
#define N_EDGES 800000
#define D 64          // NODE_DIM == MSG_DIM
#define EDIM 4
#define IN_DIM 132    // 2*D + EDIM
#define H3 192        // 3*D
#define XS 65         // XT row stride (floats): 65%32==1 -> stride-XS accesses 2-way/free

typedef unsigned short ushort;
typedef __attribute__((ext_vector_type(8))) unsigned short ushort8_t;

__device__ __forceinline__ float bf2f(ushort u) {
    union { unsigned int i; float f; } x;
    x.i = ((unsigned int)u) << 16;
    return x.f;
}
__device__ __forceinline__ ushort f2bf(float f) {
    union { float f; unsigned int i; } x;
    x.f = f;
    unsigned int r = x.i + 0x7FFFu + ((x.i >> 16) & 1u);  // round-to-nearest-even
    return (ushort)(r >> 16);
}

// ---------------- CSR build ----------------

__global__ void k_count(const int* __restrict__ dst, int* __restrict__ deg) {
    int e = blockIdx.x * blockDim.x + threadIdx.x;
    if (e < N_EDGES) atomicAdd(&deg[dst[e]], 1);
}

__global__ __launch_bounds__(256) void k_scan1(const int* __restrict__ deg,
                                               int* __restrict__ offsets,
                                               int* __restrict__ bsum) {
    __shared__ int sm[256];
    int tid = threadIdx.x;
    int i = blockIdx.x * 256 + tid;
    int x = (i < N_NODES) ? deg[i] : 0;
    sm[tid] = x;
    __syncthreads();
    for (int s = 1; s < 256; s <<= 1) {
        int v = (tid >= s) ? sm[tid - s] : 0;
        __syncthreads();
        sm[tid] += v;
        __syncthreads();
    }
    if (i < N_NODES) offsets[i] = sm[tid] - x;  // block-local exclusive
    if (tid == 255) bsum[blockIdx.x] = sm[255];
}

__global__ __launch_bounds__(256) void k_scan2(const int* __restrict__ bsum,
                                               int* __restrict__ boff, int nblk) {
    __shared__ int sm[256];
    int tid = threadIdx.x;
    int x = (tid < nblk) ? bsum[tid] : 0;
    sm[tid] = x;
    __syncthreads();
    for (int s = 1; s < 256; s <<= 1) {
        int v = (tid >= s) ? sm[tid - s] : 0;
        __syncthreads();
        sm[tid] += v;
        __syncthreads();
    }
    if (tid < nblk) boff[tid] = sm[tid] - x;  // exclusive
}

__global__ __launch_bounds__(256) void k_scan3(int* __restrict__ offsets,
                                               const int* __restrict__ boff) {
    int i = blockIdx.x * 256 + threadIdx.x;
    if (i < N_NODES) offsets[i] += boff[blockIdx.x];
}

__global__ void k_fill(const int* __restrict__ src, const int* __restrict__ dst,
                       const int* __restrict__ offsets, int* __restrict__ cursor,
                       int* __restrict__ csr_src, int* __restrict__ csr_eid) {
    int e = blockIdx.x * blockDim.x + threadIdx.x;
    if (e < N_EDGES) {
        int d = dst[e];
        int pos = offsets[d] + atomicAdd(&cursor[d], 1);
        csr_src[pos] = src[e];
        csr_eid[pos] = e;
    }
}

// ---------------- Hsum via CSR gather (no atomics): Hsum[n] = sum_{e->n} he[e] ----------
// wave per node: 16 edge slots x 4 features; he[eid] read 16B per 4-lane group.
__global__ __launch_bounds__(256) void k_hsum_csr(const float* __restrict__ he,
                                                  const int* __restrict__ csr_eid,
                                                  const int* __restrict__ offsets,
                                                  const int* __restrict__ deg,
                                                  float* __restrict__ Hsum) {
    int wave = (blockIdx.x * blockDim.x + threadIdx.x) >> 6;
    if (wave >= N_NODES) return;
    int lane = threadIdx.x & 63;
    int g = lane >> 2;   // edge slot 0..15
    int f = lane & 3;    // feature
    const int off = offsets[wave];
    const int cnt = deg[wave];
    float acc = 0.f;
    for (int e = g; e < cnt; e += 16) {
        int eid = csr_eid[off + e];
        acc += he[(size_t)eid * EDIM + f];
    }
#pragma unroll
    for (int m = 4; m <= 32; m <<= 1) acc += __shfl_xor(acc, m);
    if (g == 0) Hsum[(size_t)wave * EDIM + f] = acc;
}

// ---------------- hv -> bf16 mirror ----------------
__global__ __launch_bounds__(256) void k_prep(const float* __restrict__ hv,
                                              ushort* __restrict__ hvb) {
    int i = blockIdx.x * blockDim.x + threadIdx.x;  // one thread = 8 elements
    if (i >= (N_NODES * D) / 8) return;
    const float4* p = (const float4*)(hv + (size_t)i * 8);
    float4 a = p[0], b = p[1];
    ushort8_t o;
    o[0] = f2bf(a.x); o[1] = f2bf(a.y); o[2] = f2bf(a.z); o[3] = f2bf(a.w);
    o[4] = f2bf(b.x); o[5] = f2bf(b.y); o[6] = f2bf(b.z); o[7] = f2bf(b.w);
    *(ushort8_t*)(hvb + (size_t)i * 8) = o;
}

// ---------------- fused per-round kernel: gather-sum + GEMMs + GRU ----------------
// 512 threads = 8 waves; 64 nodes per block.
// XT[k][n], k-major, stride XS=65.
//   rows 0..63: S^T (gathered) then a^T; 64..127: hv^T (fp32); 128..131: Hsum^T.
// Phase A2 gather: wave w owns nodes w*8..w*8+7 sequentially. Per edge the whole
// wave reads one bf16 node row (64 lanes x ushort = 128B coalesced); lane k owns feature
// k, so no cross-lane reduce and the S^T store is one conflict-free LDS write per lane.
// csr_src index loads are wave-uniform (readfirstlane'd base) -> scalar pipe; 8 edges
// batched so 8 gathers are in flight per wave (R8 evidence: miss-path latency-bound).

template <int ROUND>
__global__ __launch_bounds__(512) void k_fused(const float* __restrict__ hv_in,
                                               const ushort* __restrict__ hvb_in,
                                               ushort* __restrict__ hvb_out,
                                               const int* __restrict__ csr_src,
                                               const int* __restrict__ offsets,
                                               const int* __restrict__ deg,
                                               const float* __restrict__ Hsum,
                                               const float* __restrict__ W_msg,
                                               const float* __restrict__ b_msg,
                                               const float* __restrict__ W_ih,
                                               const float* __restrict__ W_hh,
                                               const float* __restrict__ b_ih,
                                               const float* __restrict__ b_hh,
                                               float* __restrict__ hv_out) {
    __shared__ float XT[IN_DIM * XS];  // 34320 B

    const int tid = threadIdx.x;
    const int n_base = blockIdx.x * D;
    const int lane = tid & 63;

    // ---- phase A1: stage hv^T (rows 64..127, fp32) + Hsum^T (rows 128..131) ----
    {
        int nl = tid >> 3;  // 0..63
        int c8 = tid & 7;   // 8-float chunk
        int n = n_base + nl;
        if (n >= N_NODES) n = N_NODES - 1;
        const float4* Hp = (const float4*)(hv_in + (size_t)n * D);
        float4 h0 = Hp[c8 * 2], h1 = Hp[c8 * 2 + 1];
        int k0 = c8 * 8;
        XT[(64 + k0 + 0) * XS + nl] = h0.x; XT[(64 + k0 + 1) * XS + nl] = h0.y;
        XT[(64 + k0 + 2) * XS + nl] = h0.z; XT[(64 + k0 + 3) * XS + nl] = h0.w;
        XT[(64 + k0 + 4) * XS + nl] = h1.x; XT[(64 + k0 + 5) * XS + nl] = h1.y;
        XT[(64 + k0 + 6) * XS + nl] = h1.z; XT[(64 + k0 + 7) * XS + nl] = h1.w;
        if (c8 == 0) {
            float4 hs = *(const float4*)(Hsum + (size_t)n * EDIM);
            XT[128 * XS + nl] = hs.x; XT[129 * XS + nl] = hs.y;
            XT[130 * XS + nl] = hs.z; XT[131 * XS + nl] = hs.w;
        }
    }

    // ---- phase A2: gather S^T; wave w owns nodes w*8..w*8+7; lane = feature ----
    {
        const int w8 = (tid >> 6) << 3;
        for (int q = 0; q < 8; ++q) {
            const int nl = w8 + q;
            int n = n_base + nl;
            if (n >= N_NODES) n = N_NODES - 1;
            const int off = __builtin_amdgcn_readfirstlane(offsets[n]);
            const int cnt = __builtin_amdgcn_readfirstlane(deg[n]);
            float acc = 0.f;
            int e = 0;
            for (; e + 8 <= cnt; e += 8) {
                // 8 wave-uniform index loads (scalar pipe), then 8 independent gathers
                int s0 = csr_src[off + e + 0];
                int s1 = csr_src[off + e + 1];
                int s2 = csr_src[off + e + 2];
                int s3 = csr_src[off + e + 3];
                int s4 = csr_src[off + e + 4];
                int s5 = csr_src[off + e + 5];
                int s6 = csr_src[off + e + 6];
                int s7 = csr_src[off + e + 7];
                float v0 = bf2f(hvb_in[(size_t)s0 * D + lane]);
                float v1 = bf2f(hvb_in[(size_t)s1 * D + lane]);
                float v2 = bf2f(hvb_in[(size_t)s2 * D + lane]);
                float v3 = bf2f(hvb_in[(size_t)s3 * D + lane]);
                float v4 = bf2f(hvb_in[(size_t)s4 * D + lane]);
                float v5 = bf2f(hvb_in[(size_t)s5 * D + lane]);
                float v6 = bf2f(hvb_in[(size_t)s6 * D + lane]);
                float v7 = bf2f(hvb_in[(size_t)s7 * D + lane]);
                acc += ((v0 + v1) + (v2 + v3)) + ((v4 + v5) + (v6 + v7));
            }
            for (; e < cnt; ++e) {
                int s = csr_src[off + e];
                acc += bf2f(hvb_in[(size_t)s * D + lane]);
            }
            XT[lane * XS + nl] = acc;  // bank=(lane+nl)%32: 2-way, free
        }
    }
    __syncthreads();

    // ---- phase B: GEMM1 (acc1 = S@Wa + Hsum@Wc, acc2 = hv@Wb) ----
    const int w = __builtin_amdgcn_readfirstlane(tid) >> 6;  // wave id 0..7 (uniform)
    const int jb = w * 8;
    const int n = n_base + lane;
    const bool nvalid = (n < N_NODES);
    const int nc = nvalid ? n : N_NODES - 1;
    const float degf = (float)deg[nc];

    const float* __restrict__ Wm = W_msg + (size_t)ROUND * IN_DIM * D;

    float acc1[8], acc2[8];
#pragma unroll
    for (int i = 0; i < 8; ++i) { acc1[i] = 0.f; acc2[i] = 0.f; }

#pragma unroll 4
    for (int k = 0; k < 64; ++k) {
        float aS = XT[k * XS + lane];
        float aH = XT[(64 + k) * XS + lane];
        const float* wr1 = Wm + k * D + jb;
        const float* wr2 = Wm + (64 + k) * D + jb;
#pragma unroll
        for (int i = 0; i < 8; ++i) {
            acc1[i] = fmaf(aS, wr1[i], acc1[i]);
            acc2[i] = fmaf(aH, wr2[i], acc2[i]);
        }
    }
#pragma unroll
    for (int q = 0; q < 4; ++q) {
        float aQ = XT[(128 + q) * XS + lane];
        const float* wr = Wm + (128 + q) * D + jb;
#pragma unroll
        for (int i = 0; i < 8; ++i) acc1[i] = fmaf(aQ, wr[i], acc1[i]);
    }

    const float* bmp = b_msg + (size_t)ROUND * D + jb;
    float av[8];
#pragma unroll
    for (int i = 0; i < 8; ++i) av[i] = acc1[i] + degf * (acc2[i] + bmp[i]);

    __syncthreads();  // all waves done reading S rows
#pragma unroll
    for (int i = 0; i < 8; ++i) XT[(jb + i) * XS + lane] = av[i];  // a^T into rows 0..63
    __syncthreads();

    // ---- phase C: GEMM2 + GRU ----
    const float* __restrict__ Wi = W_ih + (size_t)ROUND * D * H3;
    const float* __restrict__ Wh = W_hh + (size_t)ROUND * D * H3;
    const float* bi = b_ih + (size_t)ROUND * H3;
    const float* bh = b_hh + (size_t)ROUND * H3;

    float aR[8], aZ[8], aN[8], aHN[8];
#pragma unroll
    for (int i = 0; i < 8; ++i) {
        aR[i] = bi[jb + i] + bh[jb + i];
        aZ[i] = bi[64 + jb + i] + bh[64 + jb + i];
        aN[i] = bi[128 + jb + i];
        aHN[i] = bh[128 + jb + i];
    }

#pragma unroll 4
    for (int k = 0; k < 64; ++k) {  // A = a^T rows, B = Wi
        float Aa = XT[k * XS + lane];
        const float* wr = Wi + k * H3;
#pragma unroll
        for (int i = 0; i < 8; ++i) {
            aR[i] = fmaf(Aa, wr[jb + i], aR[i]);
            aZ[i] = fmaf(Aa, wr[64 + jb + i], aZ[i]);
            aN[i] = fmaf(Aa, wr[128 + jb + i], aN[i]);
        }
    }
#pragma unroll 4
    for (int k = 0; k < 64; ++k) {  // A = hv^T rows, B = Wh
        float Ah = XT[(64 + k) * XS + lane];
        const float* wr = Wh + k * H3;
#pragma unroll
        for (int i = 0; i < 8; ++i) {
            aR[i] = fmaf(Ah, wr[jb + i], aR[i]);
            aZ[i] = fmaf(Ah, wr[64 + jb + i], aZ[i]);
            aHN[i] = fmaf(Ah, wr[128 + jb + i], aHN[i]);
        }
    }

    float o[8];
#pragma unroll
    for (int i = 0; i < 8; ++i) {
        float r = 1.f / (1.f + __expf(-aR[i]));
        float z = 1.f / (1.f + __expf(-aZ[i]));
        float nin = aN[i] + r * aHN[i];
        float nn = 2.f / (1.f + __expf(-2.f * nin)) - 1.f;  // tanh
        float hold = XT[(64 + jb + i) * XS + lane];
        o[i] = (1.f - z) * nn + z * hold;
    }
    if (nvalid) {
        float4* op = (float4*)(hv_out + (size_t)n * D + jb);
        op[0] = make_float4(o[0], o[1], o[2], o[3]);
        op[1] = make_float4(o[4], o[5], o[6], o[7]);
        if (ROUND == 0) {  // bf16 mirror for round-1 gather
            ushort8_t ob;
#pragma unroll
            for (int i = 0; i < 8; ++i) ob[i] = f2bf(o[i]);
            *(ushort8_t*)(hvb_out + (size_t)n * D + jb) = ob;
        }
    }
}

// ---------------- launch ----------------

extern "C" void kernel_launch(void* const* d_in, const int* in_sizes, int n_in,
                              void* d_out, int out_size, void* d_ws, size_t ws_size,
                              hipStream_t stream) {
    const float* hv = (const float*)d_in[0];
    const float* he = (const float*)d_in[1];
    const float* W_msg = (const float*)d_in[2];
    const float* b_msg = (const float*)d_in[3];
    const float* W_ih = (const float*)d_in[4];
    const float* W_hh = (const float*)d_in[5];
    const float* b_ih = (const float*)d_in[6];
    const float* b_hh = (const float*)d_in[7];
    const int* src = (const int*)d_in[8];
    const int* dst = (const int*)d_in[9];
    float* out = (float*)d_out;

    char* p = (char*)d_ws;
    int* deg = (int*)p;        p += (size_t)N_NODES * sizeof(int);
    int* cursor = (int*)p;     p += (size_t)N_NODES * sizeof(int);
    int* offsets = (int*)p;    p += (size_t)N_NODES * sizeof(int);
    int* bsum = (int*)p;       p += 256 * sizeof(int);
    int* boff = (int*)p;       p += 256 * sizeof(int);
    int* csr_src = (int*)p;    p += (size_t)N_EDGES * sizeof(int);
    int* csr_eid = (int*)p;    p += (size_t)N_EDGES * sizeof(int);
    float* Hsum = (float*)p;   p += (size_t)N_NODES * EDIM * sizeof(float);
    float* hv_buf = (float*)p; p += (size_t)N_NODES * D * sizeof(float);
    ushort* hvb_A = (ushort*)p; p += (size_t)N_NODES * D * sizeof(ushort);
    ushort* hvb_B = (ushort*)p; p += (size_t)N_NODES * D * sizeof(ushort);

    const int NBLK = (N_NODES + 255) / 256;  // 196

    hipMemsetAsync(deg, 0, N_NODES * sizeof(int), stream);
    hipMemsetAsync(cursor, 0, N_NODES * sizeof(int), stream);

    k_count<<<(N_EDGES + 255) / 256, 256, 0, stream>>>(dst, deg);
    k_scan1<<<NBLK, 256, 0, stream>>>(deg, offsets, bsum);
    k_scan2<<<1, 256, 0, stream>>>(bsum, boff, NBLK);
    k_scan3<<<NBLK, 256, 0, stream>>>(offsets, boff);
    k_fill<<<(N_EDGES + 255) / 256, 256, 0, stream>>>(src, dst, offsets, cursor, csr_src, csr_eid);
    k_hsum_csr<<<(N_NODES * 64 + 255) / 256, 256, 0, stream>>>(he, csr_eid, offsets, deg, Hsum);
    k_prep<<<(N_NODES * D / 8 + 255) / 256, 256, 0, stream>>>(hv, hvb_A);

    const int GBLK = (N_NODES + 63) / 64;  // 64 nodes per block, 512 threads

    // round 0: gather from hvb_A, write hv_buf (fp32) + hvb_B (bf16 mirror)
    k_fused<0><<<GBLK, 512, 0, stream>>>(hv, hvb_A, hvb_B, csr_src, offsets, deg, Hsum,
                                         W_msg, b_msg, W_ih, W_hh, b_ih, b_hh, hv_buf);

    // round 1: gather from hvb_B, write d_out
    k_fused<1><<<GBLK, 512, 0, stream>>>(hv_buf, hvb_B, (ushort*)nullptr, csr_src, offsets,
                                         deg, Hsum, W_msg, b_msg, W_ih, W_hh, b_ih, b_hh,
                                         out);
}